// Round 15
// baseline (123.292 us; speedup 1.0000x reference)
//
#include <hip/hip_runtime.h>
#include <math.h>

#define BSH 9                       // 512 nodes per bucket
#define BMASK ((1 << BSH) - 1)
#define CAP 12288                   // per-bucket pair capacity (mean 8676, sigma 93)
#define ACH 2048                    // edges per scatA block

typedef unsigned int uint;
typedef __attribute__((ext_vector_type(8))) short bf16x8;
typedef __attribute__((ext_vector_type(4))) float f32x4;
typedef __attribute__((ext_vector_type(2))) float f32x2;

static __device__ __forceinline__ unsigned short f2bf(float f) {
    uint u = __float_as_uint(f);
    return (unsigned short)((u + 0x7fffu + ((u >> 16) & 1u)) >> 16);
}

// pack 8 consecutive fp32 (two f32x4) -> bf16x8 via HW cvt (RNE), src0 -> low half
static __device__ __forceinline__ bf16x8 pack8(f32x4 a, f32x4 b) {
    uint p0, p1, p2, p3;
    asm("v_cvt_pk_bf16_f32 %0, %1, %2" : "=v"(p0) : "v"(a.x), "v"(a.y));
    asm("v_cvt_pk_bf16_f32 %0, %1, %2" : "=v"(p1) : "v"(a.z), "v"(a.w));
    asm("v_cvt_pk_bf16_f32 %0, %1, %2" : "=v"(p2) : "v"(b.x), "v"(b.y));
    asm("v_cvt_pk_bf16_f32 %0, %1, %2" : "=v"(p3) : "v"(b.z), "v"(b.w));
    uint4 u = make_uint4(p0, p1, p2, p3);
    return *(bf16x8*)&u;
}

static __device__ __forceinline__ uint pk2(float a, float b) {
    uint d;
    asm("v_cvt_pk_bf16_f32 %0, %1, %2" : "=v"(d) : "v"(a), "v"(b));
    return d;
}

static __device__ __forceinline__ f32x2 dec2(uint u) {
    f32x2 r;
    r.x = __uint_as_float(u << 16);
    r.y = __uint_as_float(u & 0xffff0000u);
    return r;
}

static __device__ __forceinline__ f32x2 abs2(f32x2 h) {
    f32x2 r;
    r.x = __uint_as_float(__float_as_uint(h.x) & 0x7fffffffu);
    r.y = __uint_as_float(__float_as_uint(h.y) & 0x7fffffffu);
    return r;
}

// sum over 4-lane quads via DPP (no LDS port): xor1 then xor2
static __device__ __forceinline__ float qsum(float p) {
    p += __uint_as_float(__builtin_amdgcn_mov_dpp(__float_as_uint(p), 0xB1, 0xF, 0xF, true));
    p += __uint_as_float(__builtin_amdgcn_mov_dpp(__float_as_uint(p), 0x4E, 0xF, 0xF, true));
    return p;
}

// ---------------- prep: fragment-major bf16 weight table ----------------
// Slot si = ks*512 + j*64 + hi*16 + lo holds W^T[n=j*16+lo][k=ks*32+hi*8 .. +8].
__global__ __launch_bounds__(256) void k_prep(const float* __restrict__ Wl,
                                              const float* __restrict__ Wr,
                                              unsigned short* __restrict__ Wt) {
    int si = blockIdx.x * 256 + threadIdx.x;   // 0..2047
    int lo = si & 15;
    int hi = (si >> 4) & 3;
    int j  = (si >> 6) & 7;
    int ks = si >> 9;
    int n  = j * 16 + lo;
    int kb = ks * 32 + hi * 8;
    const float* Wp = (n < 64) ? (Wl + n) : (Wr + (n - 64));
    unsigned short v[8];
#pragma unroll
    for (int m = 0; m < 8; ++m)
        v[m] = f2bf(Wp[(size_t)(kb + m) * 64]);
    uint4 pk;
    pk.x = (uint)v[0] | ((uint)v[1] << 16);
    pk.y = (uint)v[2] | ((uint)v[3] << 16);
    pk.z = (uint)v[4] | ((uint)v[5] << 16);
    pk.w = (uint)v[6] | ((uint)v[7] << 16);
    *(uint4*)(Wt + (size_t)si * 8) = pk;
}

// ---------------- MFMA dual GEMM: 512 thr, 8 waves x 1 m-frag (low VGPR -> deep prefetch) ----
// Output row layout (xlh and xrh), co-designed with k_fused (verified r14):
//   position 2*lo + t      <-> col t*16 + lo       (head 0)
//   position 32 + 2*lo + t <-> col 32 + t*16 + lo  (head 1)
__global__ __launch_bounds__(512) void k_gemm(
        const float* __restrict__ x, const unsigned short* __restrict__ Wt,
        const float* __restrict__ bl, const float* __restrict__ br,
        unsigned short* __restrict__ xlh, unsigned short* __restrict__ xrh, int N)
{
    const int t = threadIdx.x;
    const int base = blockIdx.x * 128;
    const int w = t >> 6;               // wave 0..7, owns rows base+w*16..+15
    const int lo = t & 15;
    const int hi = (t & 63) >> 4;
    int rowa = base + w * 16 + lo;
    const f32x4* x4 = (const f32x4*)x + (size_t)(rowa < N ? rowa : N - 1) * 32;
    const bf16x8* Wf = (const bf16x8*)Wt;

    f32x4 acc[8];
#pragma unroll
    for (int j = 0; j < 8; ++j)
        acc[j] = (f32x4){0.f, 0.f, 0.f, 0.f};

#pragma unroll
    for (int ks = 0; ks < 4; ++ks) {
        int f4 = ks * 8 + hi * 2;
        int sbase = ks * 512 + hi * 16 + lo;
        bf16x8 av = pack8(x4[f4], x4[f4 + 1]);
        bf16x8 bv[8];
#pragma unroll
        for (int j = 0; j < 8; ++j)
            bv[j] = Wf[sbase + j * 64];
#pragma unroll
        for (int j = 0; j < 8; ++j)
            acc[j] = __builtin_amdgcn_mfma_f32_16x16x32_bf16(av, bv[j], acc[j], 0, 0, 0);
    }

    // ---- epilogue: D row = base + w*16 + hi*4 + q, col = j*16 + lo ----
    float blv[4], brv[4];
#pragma unroll
    for (int t2 = 0; t2 < 4; ++t2) {
        blv[t2] = bl[t2 * 16 + lo];
        brv[t2] = br[t2 * 16 + lo];
    }
#pragma unroll
    for (int q = 0; q < 4; ++q) {
        int row = base + w * 16 + hi * 4 + q;
        if (row < N) {
            size_t rb = (size_t)row * 64;
            *(uint*)(xlh + rb + 2 * lo)      = pk2(acc[0][q] + blv[0], acc[1][q] + blv[1]);
            *(uint*)(xlh + rb + 32 + 2 * lo) = pk2(acc[2][q] + blv[2], acc[3][q] + blv[3]);
            *(uint*)(xrh + rb + 2 * lo)      = pk2(acc[4][q] + brv[0], acc[5][q] + brv[1]);
            *(uint*)(xrh + rb + 32 + 2 * lo) = pk2(acc[6][q] + brv[2], acc[7][q] + brv[3]);
        }
    }
}

// ---------------- scatA: blocked coarse scatter into bucket-grouped packed pairs ----
__global__ __launch_bounds__(256) void k_scatA(const int* __restrict__ ei, int* __restrict__ bcur,
                                               unsigned* __restrict__ pairs, int E, int T, int NB) {
    __shared__ int h[256];
    __shared__ int basem[256];
    int b0 = blockIdx.x * ACH;
    int cnt = min(ACH, T - b0);
    h[threadIdx.x] = 0;
    __syncthreads();
    for (int i = threadIdx.x; i < cnt; i += 256) {
        int t = b0 + i;
        int d = (t < E) ? ei[E + t] : (t - E);
        atomicAdd(&h[d >> BSH], 1);
    }
    __syncthreads();
    if (threadIdx.x < NB) {
        int c = h[threadIdx.x];
        basem[threadIdx.x] = c ? (threadIdx.x * CAP + atomicAdd(&bcur[threadIdx.x], c)) : 0;
    }
    __syncthreads();
    h[threadIdx.x] = 0;
    __syncthreads();
    for (int i = threadIdx.x; i < cnt; i += 256) {
        int t = b0 + i;
        int s, d;
        if (t < E) { s = ei[t]; d = ei[E + t]; } else { s = t - E; d = s; }
        int b = d >> BSH;
        int idx = atomicAdd(&h[b], 1);
        pairs[basem[b] + idx] = ((unsigned)s << BSH) | (unsigned)(d & BMASK);
    }
}

// ---------------- pass B: per-bucket degree count + scan + fine scatter + rowrng ----------------
__global__ __launch_bounds__(512) void k_scatB(const unsigned* __restrict__ pairs,
                                               const int* __restrict__ bcur,
                                               int* __restrict__ src_s, int2* __restrict__ rowrng, int N) {
    __shared__ int cnt[512];
    __shared__ int sm[512];
    __shared__ int lofs[512];
    int b = blockIdx.x;
    int beg = b * CAP, end = beg + bcur[b];
    int nbase = b << BSH;
    cnt[threadIdx.x] = 0;
    __syncthreads();
    for (int i = beg + threadIdx.x; i < end; i += 512)
        atomicAdd(&cnt[pairs[i] & BMASK], 1);
    __syncthreads();
    int v = cnt[threadIdx.x];
    sm[threadIdx.x] = v;
    __syncthreads();
    int acc = v;
    for (int off = 1; off < 512; off <<= 1) {
        int t = (threadIdx.x >= off) ? sm[threadIdx.x - off] : 0;
        __syncthreads();
        acc += t;
        sm[threadIdx.x] = acc;
        __syncthreads();
    }
    int excl = acc - v;
    lofs[threadIdx.x] = excl;
    int n = nbase + threadIdx.x;
    if (n < N) rowrng[n] = make_int2(beg + excl, beg + excl + v);
    cnt[threadIdx.x] = 0;
    __syncthreads();
    for (int i = beg + threadIdx.x; i < end; i += 512) {
        unsigned p = pairs[i];
        int dl = p & BMASK;
        int idx = atomicAdd(&cnt[dl], 1);
        src_s[beg + lofs[dl] + idx] = p >> BSH;
    }
}

// ---------------- fused attn + softmax + aggregation + silu ----------------
// 8 lanes per node; lanes 0-3 head0, 4-7 head1 (head-blocked transposed row layout, r14).
// 16 edges in flight.
__global__ __launch_bounds__(256) void k_fused(const int2* __restrict__ rowrng,
        const int* __restrict__ src_s, const unsigned short* __restrict__ xlh,
        const unsigned short* __restrict__ xrh, const float* __restrict__ att,
        const float* __restrict__ bias, float* __restrict__ out, int N)
{
    int n = blockIdx.x * 32 + (threadIdx.x >> 3);
    int jf = threadIdx.x & 7;
    if (n >= N) return;
    int hsel = jf >> 2, l4 = jf & 3;
    const uint4* xl4 = (const uint4*)xlh + jf;
    f32x2 xr2[4], a06[4], a04[4];
    {
        uint4 u = ((const uint4*)xrh)[(size_t)n * 8 + jf];
        xr2[0] = dec2(u.x); xr2[1] = dec2(u.y);
        xr2[2] = dec2(u.z); xr2[3] = dec2(u.w);
        int cb = hsel * 32 + 4 * l4;
#pragma unroll
        for (int k = 0; k < 4; ++k) {
            float c0 = att[cb + k], c1 = att[cb + 16 + k];
            a06[k] = (f32x2){0.6f * c0, 0.6f * c1};
            a04[k] = (f32x2){0.4f * c0, 0.4f * c1};
        }
    }
    int2 rr = rowrng[n];
    float ssum = 0.f;
    f32x2 acc2[4] = {(f32x2){0.f,0.f}, (f32x2){0.f,0.f}, (f32x2){0.f,0.f}, (f32x2){0.f,0.f}};

#define EDGE_BODY(u)                                                      \
    {                                                                     \
        f32x2 v0 = dec2((u).x), v1 = dec2((u).y), v2 = dec2((u).z), v3 = dec2((u).w); \
        f32x2 h0 = v0 + xr2[0], h1 = v1 + xr2[1], h2 = v2 + xr2[2], h3 = v3 + xr2[3]; \
        f32x2 pa = h0 * a06[0]; pa += h1 * a06[1]; pa += h2 * a06[2]; pa += h3 * a06[3]; \
        pa += abs2(h0) * a04[0]; pa += abs2(h1) * a04[1];                 \
        pa += abs2(h2) * a04[2]; pa += abs2(h3) * a04[3];                 \
        float p = pa.x + pa.y;                                            \
        p = qsum(p);                                                      \
        float wq = __expf(p);                                             \
        ssum += wq;                                                       \
        f32x2 ws = (f32x2){wq, wq};                                       \
        acc2[0] += ws * v0; acc2[1] += ws * v1;                           \
        acc2[2] += ws * v2; acc2[3] += ws * v3;                           \
    }

    int i = rr.x;
    for (; i + 16 <= rr.y; i += 16) {
        uint4 u[16];
#pragma unroll
        for (int q = 0; q < 16; ++q)
            u[q] = xl4[((uint)src_s[i + q] << 3)];
#pragma unroll
        for (int q = 0; q < 16; ++q)
            EDGE_BODY(u[q]);
    }
    if (i + 8 <= rr.y) {
        uint4 u[8];
#pragma unroll
        for (int q = 0; q < 8; ++q)
            u[q] = xl4[((uint)src_s[i + q] << 3)];
#pragma unroll
        for (int q = 0; q < 8; ++q)
            EDGE_BODY(u[q]);
        i += 8;
    }
    if (i + 4 <= rr.y) {
        uint4 u[4];
#pragma unroll
        for (int q = 0; q < 4; ++q)
            u[q] = xl4[((uint)src_s[i + q] << 3)];
#pragma unroll
        for (int q = 0; q < 4; ++q)
            EDGE_BODY(u[q]);
        i += 4;
    }
    for (; i < rr.y; ++i) {
        uint4 u0 = xl4[((uint)src_s[i] << 3)];
        EDGE_BODY(u0);
    }
#undef EDGE_BODY

    float inv = 1.f / ssum;
    float o[8];
#pragma unroll
    for (int q = 0; q < 4; ++q) {
        float vx = acc2[q].x * inv, vy = acc2[q].y * inv;
        o[2 * q]     = (vx + __shfl_xor(vx, 4)) * 0.5f;   // head-mean: partner holds col+32
        o[2 * q + 1] = (vy + __shfl_xor(vy, 4)) * 0.5f;
    }
    if (jf < 4) {
        float4 b0 = ((const float4*)bias)[l4];
        float4 b1 = *(const float4*)(bias + 16 + 4 * l4);
        float4 r0, r1;
        r0.x = o[0] + b0.x; r0.y = o[2] + b0.y; r0.z = o[4] + b0.z; r0.w = o[6] + b0.w;
        r1.x = o[1] + b1.x; r1.y = o[3] + b1.y; r1.z = o[5] + b1.z; r1.w = o[7] + b1.w;
        r0.x = r0.x / (1.f + __expf(-r0.x));
        r0.y = r0.y / (1.f + __expf(-r0.y));
        r0.z = r0.z / (1.f + __expf(-r0.z));
        r0.w = r0.w / (1.f + __expf(-r0.w));
        r1.x = r1.x / (1.f + __expf(-r1.x));
        r1.y = r1.y / (1.f + __expf(-r1.y));
        r1.z = r1.z / (1.f + __expf(-r1.z));
        r1.w = r1.w / (1.f + __expf(-r1.w));
        ((float4*)out)[(size_t)n * 8 + l4]     = r0;
        ((float4*)out)[(size_t)n * 8 + 4 + l4] = r1;
    }
}

extern "C" void kernel_launch(void* const* d_in, const int* in_sizes, int n_in,
                              void* d_out, int out_size, void* d_ws, size_t ws_size,
                              hipStream_t stream) {
    const float* x    = (const float*)d_in[0];
    const float* Wl   = (const float*)d_in[1];
    const float* bl   = (const float*)d_in[2];
    const float* Wr   = (const float*)d_in[3];
    const float* br   = (const float*)d_in[4];
    const float* att  = (const float*)d_in[5];
    const float* bias = (const float*)d_in[6];
    const int*   ei   = (const int*)d_in[7];
    float* out = (float*)d_out;

    const int N = in_sizes[0] / 128;
    const int E = in_sizes[7] / 2;
    const int T = E + N;                          // edges incl. self loops
    const int NB = (N + (1 << BSH) - 1) >> BSH;   // 196 buckets

    char* p = (char*)d_ws;
    auto take = [&](size_t bytes) {
        char* r = p;
        p += (bytes + 255) & ~(size_t)255;
        return r;
    };
    unsigned short* xlh = (unsigned short*)take((size_t)N * 64 * 2);
    unsigned short* xrh = (unsigned short*)take((size_t)N * 64 * 2);
    unsigned* pairs  = (unsigned*)take((size_t)NB * CAP * 4);
    int*      src_s  = (int*)take((size_t)NB * CAP * 4);
    int2*     rowrng = (int2*)take((size_t)N * 8);
    int*      bcur   = (int*)take((size_t)NB * 4);
    unsigned short* Wt = (unsigned short*)take((size_t)128 * 128 * 2);

    hipMemsetAsync(bcur, 0, (size_t)NB * 4, stream);
    k_prep <<<8,                   256, 0, stream>>>(Wl, Wr, Wt);
    k_gemm <<<(N + 127) / 128,     512, 0, stream>>>(x, Wt, bl, br, xlh, xrh, N);
    k_scatA<<<(T + ACH - 1) / ACH, 256, 0, stream>>>(ei, bcur, pairs, E, T, NB);
    k_scatB<<<NB,                  512, 0, stream>>>(pairs, bcur, src_s, rowrng, N);
    k_fused<<<(N + 31) / 32,       256, 0, stream>>>(rowrng, src_s, xlh, xrh, att, bias, out, N);
}

// Round 16
// 120.187 us; speedup vs baseline: 1.0258x; 1.0258x over previous
//
#include <hip/hip_runtime.h>
#include <math.h>

#define BSH 9                       // 512 nodes per bucket
#define BMASK ((1 << BSH) - 1)
#define CAP 12288                   // per-bucket pair capacity (mean 8676, sigma 93)
#define ACH 2048                    // edges per scatA block

typedef unsigned int uint;
typedef __attribute__((ext_vector_type(8))) short bf16x8;
typedef __attribute__((ext_vector_type(4))) float f32x4;
typedef __attribute__((ext_vector_type(2))) float f32x2;

static __device__ __forceinline__ unsigned short f2bf(float f) {
    uint u = __float_as_uint(f);
    return (unsigned short)((u + 0x7fffu + ((u >> 16) & 1u)) >> 16);
}

// pack 8 consecutive fp32 (two f32x4) -> bf16x8 via HW cvt (RNE), src0 -> low half
static __device__ __forceinline__ bf16x8 pack8(f32x4 a, f32x4 b) {
    uint p0, p1, p2, p3;
    asm("v_cvt_pk_bf16_f32 %0, %1, %2" : "=v"(p0) : "v"(a.x), "v"(a.y));
    asm("v_cvt_pk_bf16_f32 %0, %1, %2" : "=v"(p1) : "v"(a.z), "v"(a.w));
    asm("v_cvt_pk_bf16_f32 %0, %1, %2" : "=v"(p2) : "v"(b.x), "v"(b.y));
    asm("v_cvt_pk_bf16_f32 %0, %1, %2" : "=v"(p3) : "v"(b.z), "v"(b.w));
    uint4 u = make_uint4(p0, p1, p2, p3);
    return *(bf16x8*)&u;
}

static __device__ __forceinline__ uint pk2(float a, float b) {
    uint d;
    asm("v_cvt_pk_bf16_f32 %0, %1, %2" : "=v"(d) : "v"(a), "v"(b));
    return d;
}

static __device__ __forceinline__ f32x2 dec2(uint u) {
    f32x2 r;
    r.x = __uint_as_float(u << 16);
    r.y = __uint_as_float(u & 0xffff0000u);
    return r;
}

static __device__ __forceinline__ f32x2 abs2(f32x2 h) {
    f32x2 r;
    r.x = __uint_as_float(__float_as_uint(h.x) & 0x7fffffffu);
    r.y = __uint_as_float(__float_as_uint(h.y) & 0x7fffffffu);
    return r;
}

// sum over 4-lane quads via DPP (no LDS port): xor1 then xor2
static __device__ __forceinline__ float qsum(float p) {
    p += __uint_as_float(__builtin_amdgcn_mov_dpp(__float_as_uint(p), 0xB1, 0xF, 0xF, true));
    p += __uint_as_float(__builtin_amdgcn_mov_dpp(__float_as_uint(p), 0x4E, 0xF, 0xF, true));
    return p;
}

// ---------------- prep: fragment-major bf16 weight table ----------------
// Slot si = ks*512 + j*64 + hi*16 + lo holds W^T[n=j*16+lo][k=ks*32+hi*8 .. +8].
__global__ __launch_bounds__(256) void k_prep(const float* __restrict__ Wl,
                                              const float* __restrict__ Wr,
                                              unsigned short* __restrict__ Wt) {
    int si = blockIdx.x * 256 + threadIdx.x;   // 0..2047
    int lo = si & 15;
    int hi = (si >> 4) & 3;
    int j  = (si >> 6) & 7;
    int ks = si >> 9;
    int n  = j * 16 + lo;
    int kb = ks * 32 + hi * 8;
    const float* Wp = (n < 64) ? (Wl + n) : (Wr + (n - 64));
    unsigned short v[8];
#pragma unroll
    for (int m = 0; m < 8; ++m)
        v[m] = f2bf(Wp[(size_t)(kb + m) * 64]);
    uint4 pk;
    pk.x = (uint)v[0] | ((uint)v[1] << 16);
    pk.y = (uint)v[2] | ((uint)v[3] << 16);
    pk.z = (uint)v[4] | ((uint)v[5] << 16);
    pk.w = (uint)v[6] | ((uint)v[7] << 16);
    *(uint4*)(Wt + (size_t)si * 8) = pk;
}

// ---------------- MFMA dual GEMM: BM=64, 8 waves = 4 row-groups x 2 col-halves ----------
// Wave (wr, wc): rows base+wr*16..+15, cols wc*64..+63 (wc=0 -> xlh, wc=1 -> xrh).
// Low VGPR (acc[4]+bv[4]) -> compiler can prefetch next ks phase under MFMAs.
// Output row layout (xlh and xrh), co-designed with k_fused (verified r14):
//   position 2*lo + t      <-> col t*16 + lo       (head 0)
//   position 32 + 2*lo + t <-> col 32 + t*16 + lo  (head 1)
__global__ __launch_bounds__(512) void k_gemm(
        const float* __restrict__ x, const unsigned short* __restrict__ Wt,
        const float* __restrict__ bl, const float* __restrict__ br,
        unsigned short* __restrict__ xlh, unsigned short* __restrict__ xrh, int N)
{
    const int t = threadIdx.x;
    const int base = blockIdx.x * 64;
    const int w  = t >> 6;              // wave 0..7
    const int wr = w >> 1;              // row group 0..3
    const int wc = w & 1;               // col half: 0 = xl, 1 = xr
    const int lo = t & 15;
    const int hi = (t & 63) >> 4;
    int rowa = base + wr * 16 + lo;
    const f32x4* x4 = (const f32x4*)x + (size_t)(rowa < N ? rowa : N - 1) * 32;
    const bf16x8* Wf = (const bf16x8*)Wt;

    f32x4 acc[4];
#pragma unroll
    for (int j = 0; j < 4; ++j)
        acc[j] = (f32x4){0.f, 0.f, 0.f, 0.f};

#pragma unroll
    for (int ks = 0; ks < 4; ++ks) {
        int f4 = ks * 8 + hi * 2;
        int sbase = ks * 512 + wc * 256 + hi * 16 + lo;   // wc*4 frags * 64 slots
        bf16x8 av = pack8(x4[f4], x4[f4 + 1]);
        bf16x8 bv[4];
#pragma unroll
        for (int j = 0; j < 4; ++j)
            bv[j] = Wf[sbase + j * 64];
#pragma unroll
        for (int j = 0; j < 4; ++j)
            acc[j] = __builtin_amdgcn_mfma_f32_16x16x32_bf16(av, bv[j], acc[j], 0, 0, 0);
    }

    // ---- epilogue: D row = base + wr*16 + hi*4 + q, col = (wc*4+j)*16 + lo ----
    const float* bb = wc ? br : bl;
    unsigned short* dst = wc ? xrh : xlh;
    float bv4[4];
#pragma unroll
    for (int t2 = 0; t2 < 4; ++t2)
        bv4[t2] = bb[t2 * 16 + lo];
#pragma unroll
    for (int q = 0; q < 4; ++q) {
        int row = base + wr * 16 + hi * 4 + q;
        if (row < N) {
            size_t rb = (size_t)row * 64;
            *(uint*)(dst + rb + 2 * lo)      = pk2(acc[0][q] + bv4[0], acc[1][q] + bv4[1]);
            *(uint*)(dst + rb + 32 + 2 * lo) = pk2(acc[2][q] + bv4[2], acc[3][q] + bv4[3]);
        }
    }
}

// ---------------- scatA: blocked coarse scatter into bucket-grouped packed pairs ----
__global__ __launch_bounds__(256) void k_scatA(const int* __restrict__ ei, int* __restrict__ bcur,
                                               unsigned* __restrict__ pairs, int E, int T, int NB) {
    __shared__ int h[256];
    __shared__ int basem[256];
    int b0 = blockIdx.x * ACH;
    int cnt = min(ACH, T - b0);
    h[threadIdx.x] = 0;
    __syncthreads();
    for (int i = threadIdx.x; i < cnt; i += 256) {
        int t = b0 + i;
        int d = (t < E) ? ei[E + t] : (t - E);
        atomicAdd(&h[d >> BSH], 1);
    }
    __syncthreads();
    if (threadIdx.x < NB) {
        int c = h[threadIdx.x];
        basem[threadIdx.x] = c ? (threadIdx.x * CAP + atomicAdd(&bcur[threadIdx.x], c)) : 0;
    }
    __syncthreads();
    h[threadIdx.x] = 0;
    __syncthreads();
    for (int i = threadIdx.x; i < cnt; i += 256) {
        int t = b0 + i;
        int s, d;
        if (t < E) { s = ei[t]; d = ei[E + t]; } else { s = t - E; d = s; }
        int b = d >> BSH;
        int idx = atomicAdd(&h[b], 1);
        pairs[basem[b] + idx] = ((unsigned)s << BSH) | (unsigned)(d & BMASK);
    }
}

// ---------------- pass B: per-bucket degree count + scan + fine scatter + rowrng ----------------
__global__ __launch_bounds__(512) void k_scatB(const unsigned* __restrict__ pairs,
                                               const int* __restrict__ bcur,
                                               int* __restrict__ src_s, int2* __restrict__ rowrng, int N) {
    __shared__ int cnt[512];
    __shared__ int sm[512];
    __shared__ int lofs[512];
    int b = blockIdx.x;
    int beg = b * CAP, end = beg + bcur[b];
    int nbase = b << BSH;
    cnt[threadIdx.x] = 0;
    __syncthreads();
    for (int i = beg + threadIdx.x; i < end; i += 512)
        atomicAdd(&cnt[pairs[i] & BMASK], 1);
    __syncthreads();
    int v = cnt[threadIdx.x];
    sm[threadIdx.x] = v;
    __syncthreads();
    int acc = v;
    for (int off = 1; off < 512; off <<= 1) {
        int t = (threadIdx.x >= off) ? sm[threadIdx.x - off] : 0;
        __syncthreads();
        acc += t;
        sm[threadIdx.x] = acc;
        __syncthreads();
    }
    int excl = acc - v;
    lofs[threadIdx.x] = excl;
    int n = nbase + threadIdx.x;
    if (n < N) rowrng[n] = make_int2(beg + excl, beg + excl + v);
    cnt[threadIdx.x] = 0;
    __syncthreads();
    for (int i = beg + threadIdx.x; i < end; i += 512) {
        unsigned p = pairs[i];
        int dl = p & BMASK;
        int idx = atomicAdd(&cnt[dl], 1);
        src_s[beg + lofs[dl] + idx] = p >> BSH;
    }
}

// ---------------- fused attn + softmax + aggregation + silu ----------------
// 8 lanes per node; lanes 0-3 head0, 4-7 head1 (head-blocked transposed row layout, r14).
// 8 edges in flight (proven best: VGPR ~48, occupancy ~36%).
__global__ __launch_bounds__(256) void k_fused(const int2* __restrict__ rowrng,
        const int* __restrict__ src_s, const unsigned short* __restrict__ xlh,
        const unsigned short* __restrict__ xrh, const float* __restrict__ att,
        const float* __restrict__ bias, float* __restrict__ out, int N)
{
    int n = blockIdx.x * 32 + (threadIdx.x >> 3);
    int jf = threadIdx.x & 7;
    if (n >= N) return;
    int hsel = jf >> 2, l4 = jf & 3;
    const uint4* xl4 = (const uint4*)xlh + jf;
    f32x2 xr2[4], a06[4], a04[4];
    {
        uint4 u = ((const uint4*)xrh)[(size_t)n * 8 + jf];
        xr2[0] = dec2(u.x); xr2[1] = dec2(u.y);
        xr2[2] = dec2(u.z); xr2[3] = dec2(u.w);
        int cb = hsel * 32 + 4 * l4;
#pragma unroll
        for (int k = 0; k < 4; ++k) {
            float c0 = att[cb + k], c1 = att[cb + 16 + k];
            a06[k] = (f32x2){0.6f * c0, 0.6f * c1};
            a04[k] = (f32x2){0.4f * c0, 0.4f * c1};
        }
    }
    int2 rr = rowrng[n];
    float ssum = 0.f;
    f32x2 acc2[4] = {(f32x2){0.f,0.f}, (f32x2){0.f,0.f}, (f32x2){0.f,0.f}, (f32x2){0.f,0.f}};

#define EDGE_BODY(u)                                                      \
    {                                                                     \
        f32x2 v0 = dec2((u).x), v1 = dec2((u).y), v2 = dec2((u).z), v3 = dec2((u).w); \
        f32x2 h0 = v0 + xr2[0], h1 = v1 + xr2[1], h2 = v2 + xr2[2], h3 = v3 + xr2[3]; \
        f32x2 pa = h0 * a06[0]; pa += h1 * a06[1]; pa += h2 * a06[2]; pa += h3 * a06[3]; \
        pa += abs2(h0) * a04[0]; pa += abs2(h1) * a04[1];                 \
        pa += abs2(h2) * a04[2]; pa += abs2(h3) * a04[3];                 \
        float p = pa.x + pa.y;                                            \
        p = qsum(p);                                                      \
        float wq = __expf(p);                                             \
        ssum += wq;                                                       \
        f32x2 ws = (f32x2){wq, wq};                                       \
        acc2[0] += ws * v0; acc2[1] += ws * v1;                           \
        acc2[2] += ws * v2; acc2[3] += ws * v3;                           \
    }

    int i = rr.x;
    for (; i + 8 <= rr.y; i += 8) {
        uint4 u[8];
#pragma unroll
        for (int q = 0; q < 8; ++q)
            u[q] = xl4[((uint)src_s[i + q] << 3)];
#pragma unroll
        for (int q = 0; q < 8; ++q)
            EDGE_BODY(u[q]);
    }
    if (i + 4 <= rr.y) {
        uint4 u[4];
#pragma unroll
        for (int q = 0; q < 4; ++q)
            u[q] = xl4[((uint)src_s[i + q] << 3)];
#pragma unroll
        for (int q = 0; q < 4; ++q)
            EDGE_BODY(u[q]);
        i += 4;
    }
    for (; i < rr.y; ++i) {
        uint4 u0 = xl4[((uint)src_s[i] << 3)];
        EDGE_BODY(u0);
    }
#undef EDGE_BODY

    float inv = 1.f / ssum;
    float o[8];
#pragma unroll
    for (int q = 0; q < 4; ++q) {
        float vx = acc2[q].x * inv, vy = acc2[q].y * inv;
        o[2 * q]     = (vx + __shfl_xor(vx, 4)) * 0.5f;   // head-mean: partner holds col+32
        o[2 * q + 1] = (vy + __shfl_xor(vy, 4)) * 0.5f;
    }
    if (jf < 4) {
        float4 b0 = ((const float4*)bias)[l4];
        float4 b1 = *(const float4*)(bias + 16 + 4 * l4);
        float4 r0, r1;
        r0.x = o[0] + b0.x; r0.y = o[2] + b0.y; r0.z = o[4] + b0.z; r0.w = o[6] + b0.w;
        r1.x = o[1] + b1.x; r1.y = o[3] + b1.y; r1.z = o[5] + b1.z; r1.w = o[7] + b1.w;
        r0.x = r0.x / (1.f + __expf(-r0.x));
        r0.y = r0.y / (1.f + __expf(-r0.y));
        r0.z = r0.z / (1.f + __expf(-r0.z));
        r0.w = r0.w / (1.f + __expf(-r0.w));
        r1.x = r1.x / (1.f + __expf(-r1.x));
        r1.y = r1.y / (1.f + __expf(-r1.y));
        r1.z = r1.z / (1.f + __expf(-r1.z));
        r1.w = r1.w / (1.f + __expf(-r1.w));
        ((float4*)out)[(size_t)n * 8 + l4]     = r0;
        ((float4*)out)[(size_t)n * 8 + 4 + l4] = r1;
    }
}

extern "C" void kernel_launch(void* const* d_in, const int* in_sizes, int n_in,
                              void* d_out, int out_size, void* d_ws, size_t ws_size,
                              hipStream_t stream) {
    const float* x    = (const float*)d_in[0];
    const float* Wl   = (const float*)d_in[1];
    const float* bl   = (const float*)d_in[2];
    const float* Wr   = (const float*)d_in[3];
    const float* br   = (const float*)d_in[4];
    const float* att  = (const float*)d_in[5];
    const float* bias = (const float*)d_in[6];
    const int*   ei   = (const int*)d_in[7];
    float* out = (float*)d_out;

    const int N = in_sizes[0] / 128;
    const int E = in_sizes[7] / 2;
    const int T = E + N;                          // edges incl. self loops
    const int NB = (N + (1 << BSH) - 1) >> BSH;   // 196 buckets

    char* p = (char*)d_ws;
    auto take = [&](size_t bytes) {
        char* r = p;
        p += (bytes + 255) & ~(size_t)255;
        return r;
    };
    unsigned short* xlh = (unsigned short*)take((size_t)N * 64 * 2);
    unsigned short* xrh = (unsigned short*)take((size_t)N * 64 * 2);
    unsigned* pairs  = (unsigned*)take((size_t)NB * CAP * 4);
    int*      src_s  = (int*)take((size_t)NB * CAP * 4);
    int2*     rowrng = (int2*)take((size_t)N * 8);
    int*      bcur   = (int*)take((size_t)NB * 4);
    unsigned short* Wt = (unsigned short*)take((size_t)128 * 128 * 2);

    hipMemsetAsync(bcur, 0, (size_t)NB * 4, stream);
    k_prep <<<8,                   256, 0, stream>>>(Wl, Wr, Wt);
    k_gemm <<<(N + 63) / 64,       512, 0, stream>>>(x, Wt, bl, br, xlh, xrh, N);
    k_scatA<<<(T + ACH - 1) / ACH, 256, 0, stream>>>(ei, bcur, pairs, E, T, NB);
    k_scatB<<<NB,                  512, 0, stream>>>(pairs, bcur, src_s, rowrng, N);
    k_fused<<<(N + 31) / 32,       256, 0, stream>>>(rowrng, src_s, xlh, xrh, att, bias, out, N);
}

// Round 17
// 119.735 us; speedup vs baseline: 1.0297x; 1.0038x over previous
//
#include <hip/hip_runtime.h>
#include <math.h>

#define BSH 8                       // 256 nodes per bucket
#define BMASK ((1 << BSH) - 1)
#define CAP 6144                    // per-bucket pair capacity (mean 4348, sigma 66)
#define ACH 2048                    // edges per scatA block

typedef unsigned int uint;
typedef __attribute__((ext_vector_type(8))) short bf16x8;
typedef __attribute__((ext_vector_type(4))) float f32x4;
typedef __attribute__((ext_vector_type(2))) float f32x2;

static __device__ __forceinline__ unsigned short f2bf(float f) {
    uint u = __float_as_uint(f);
    return (unsigned short)((u + 0x7fffu + ((u >> 16) & 1u)) >> 16);
}

// pack 8 consecutive fp32 (two f32x4) -> bf16x8 via HW cvt (RNE), src0 -> low half
static __device__ __forceinline__ bf16x8 pack8(f32x4 a, f32x4 b) {
    uint p0, p1, p2, p3;
    asm("v_cvt_pk_bf16_f32 %0, %1, %2" : "=v"(p0) : "v"(a.x), "v"(a.y));
    asm("v_cvt_pk_bf16_f32 %0, %1, %2" : "=v"(p1) : "v"(a.z), "v"(a.w));
    asm("v_cvt_pk_bf16_f32 %0, %1, %2" : "=v"(p2) : "v"(b.x), "v"(b.y));
    asm("v_cvt_pk_bf16_f32 %0, %1, %2" : "=v"(p3) : "v"(b.z), "v"(b.w));
    uint4 u = make_uint4(p0, p1, p2, p3);
    return *(bf16x8*)&u;
}

static __device__ __forceinline__ uint pk2(float a, float b) {
    uint d;
    asm("v_cvt_pk_bf16_f32 %0, %1, %2" : "=v"(d) : "v"(a), "v"(b));
    return d;
}

static __device__ __forceinline__ f32x2 dec2(uint u) {
    f32x2 r;
    r.x = __uint_as_float(u << 16);
    r.y = __uint_as_float(u & 0xffff0000u);
    return r;
}

static __device__ __forceinline__ f32x2 abs2(f32x2 h) {
    f32x2 r;
    r.x = __uint_as_float(__float_as_uint(h.x) & 0x7fffffffu);
    r.y = __uint_as_float(__float_as_uint(h.y) & 0x7fffffffu);
    return r;
}

// sum over 4-lane quads via DPP (no LDS port): xor1 then xor2
static __device__ __forceinline__ float qsum(float p) {
    p += __uint_as_float(__builtin_amdgcn_mov_dpp(__float_as_uint(p), 0xB1, 0xF, 0xF, true));
    p += __uint_as_float(__builtin_amdgcn_mov_dpp(__float_as_uint(p), 0x4E, 0xF, 0xF, true));
    return p;
}

// ---------------- prep: fragment-major bf16 weight table + bcur zeroing ----------------
// Slot si = ks*512 + j*64 + hi*16 + lo holds W^T[n=j*16+lo][k=ks*32+hi*8 .. +8].
__global__ __launch_bounds__(256) void k_prep(const float* __restrict__ Wl,
                                              const float* __restrict__ Wr,
                                              unsigned short* __restrict__ Wt,
                                              int* __restrict__ bcur, int NB) {
    if (blockIdx.x == 0)
        for (int i = threadIdx.x; i < NB; i += 256) bcur[i] = 0;
    int si = blockIdx.x * 256 + threadIdx.x;   // 0..2047
    int lo = si & 15;
    int hi = (si >> 4) & 3;
    int j  = (si >> 6) & 7;
    int ks = si >> 9;
    int n  = j * 16 + lo;
    int kb = ks * 32 + hi * 8;
    const float* Wp = (n < 64) ? (Wl + n) : (Wr + (n - 64));
    unsigned short v[8];
#pragma unroll
    for (int m = 0; m < 8; ++m)
        v[m] = f2bf(Wp[(size_t)(kb + m) * 64]);
    uint4 pk;
    pk.x = (uint)v[0] | ((uint)v[1] << 16);
    pk.y = (uint)v[2] | ((uint)v[3] << 16);
    pk.z = (uint)v[4] | ((uint)v[5] << 16);
    pk.w = (uint)v[6] | ((uint)v[7] << 16);
    *(uint4*)(Wt + (size_t)si * 8) = pk;
}

// ---------------- MFMA dual GEMM: BM=64, 8 waves = 4 row-groups x 2 col-halves ----------
// Wave (wr, wc): rows base+wr*16..+15, cols wc*64..+63 (wc=0 -> xlh, wc=1 -> xrh).
// Output row layout (xlh and xrh), co-designed with k_fused (verified r14):
//   position 2*lo + t      <-> col t*16 + lo       (head 0)
//   position 32 + 2*lo + t <-> col 32 + t*16 + lo  (head 1)
__global__ __launch_bounds__(512) void k_gemm(
        const float* __restrict__ x, const unsigned short* __restrict__ Wt,
        const float* __restrict__ bl, const float* __restrict__ br,
        unsigned short* __restrict__ xlh, unsigned short* __restrict__ xrh, int N)
{
    const int t = threadIdx.x;
    const int base = blockIdx.x * 64;
    const int w  = t >> 6;              // wave 0..7
    const int wr = w >> 1;              // row group 0..3
    const int wc = w & 1;               // col half: 0 = xl, 1 = xr
    const int lo = t & 15;
    const int hi = (t & 63) >> 4;
    int rowa = base + wr * 16 + lo;
    const f32x4* x4 = (const f32x4*)x + (size_t)(rowa < N ? rowa : N - 1) * 32;
    const bf16x8* Wf = (const bf16x8*)Wt;

    f32x4 acc[4];
#pragma unroll
    for (int j = 0; j < 4; ++j)
        acc[j] = (f32x4){0.f, 0.f, 0.f, 0.f};

#pragma unroll
    for (int ks = 0; ks < 4; ++ks) {
        int f4 = ks * 8 + hi * 2;
        int sbase = ks * 512 + wc * 256 + hi * 16 + lo;   // wc*4 frags * 64 slots
        bf16x8 av = pack8(x4[f4], x4[f4 + 1]);
        bf16x8 bv[4];
#pragma unroll
        for (int j = 0; j < 4; ++j)
            bv[j] = Wf[sbase + j * 64];
#pragma unroll
        for (int j = 0; j < 4; ++j)
            acc[j] = __builtin_amdgcn_mfma_f32_16x16x32_bf16(av, bv[j], acc[j], 0, 0, 0);
    }

    // ---- epilogue: D row = base + wr*16 + hi*4 + q, col = (wc*4+j)*16 + lo ----
    const float* bb = wc ? br : bl;
    unsigned short* dst = wc ? xrh : xlh;
    float bv4[4];
#pragma unroll
    for (int t2 = 0; t2 < 4; ++t2)
        bv4[t2] = bb[t2 * 16 + lo];
#pragma unroll
    for (int q = 0; q < 4; ++q) {
        int row = base + wr * 16 + hi * 4 + q;
        if (row < N) {
            size_t rb = (size_t)row * 64;
            *(uint*)(dst + rb + 2 * lo)      = pk2(acc[0][q] + bv4[0], acc[1][q] + bv4[1]);
            *(uint*)(dst + rb + 32 + 2 * lo) = pk2(acc[2][q] + bv4[2], acc[3][q] + bv4[3]);
        }
    }
}

// ---------------- scatA: blocked coarse scatter into bucket-grouped packed pairs ----
__global__ __launch_bounds__(256) void k_scatA(const int* __restrict__ ei, int* __restrict__ bcur,
                                               unsigned* __restrict__ pairs, int E, int T, int NB) {
    __shared__ int h[512];
    __shared__ int basem[512];
    int b0 = blockIdx.x * ACH;
    int cnt = min(ACH, T - b0);
    h[threadIdx.x] = 0; h[threadIdx.x + 256] = 0;
    __syncthreads();
    for (int i = threadIdx.x; i < cnt; i += 256) {
        int t = b0 + i;
        int d = (t < E) ? ei[E + t] : (t - E);
        atomicAdd(&h[d >> BSH], 1);
    }
    __syncthreads();
    for (int b = threadIdx.x; b < NB; b += 256) {
        int c = h[b];
        basem[b] = c ? (b * CAP + atomicAdd(&bcur[b], c)) : 0;
    }
    __syncthreads();
    h[threadIdx.x] = 0; h[threadIdx.x + 256] = 0;
    __syncthreads();
    for (int i = threadIdx.x; i < cnt; i += 256) {
        int t = b0 + i;
        int s, d;
        if (t < E) { s = ei[t]; d = ei[E + t]; } else { s = t - E; d = s; }
        int b = d >> BSH;
        int idx = atomicAdd(&h[b], 1);
        pairs[basem[b] + idx] = ((unsigned)s << BSH) | (unsigned)(d & BMASK);
    }
}

// ---------------- pass B: per-bucket degree count + scan + fine scatter + rowrng ----------------
// 391 blocks x 512 threads; 256-wide scan (threads >=256 idle there, help in passes).
__global__ __launch_bounds__(512) void k_scatB(const unsigned* __restrict__ pairs,
                                               const int* __restrict__ bcur,
                                               int* __restrict__ src_s, int2* __restrict__ rowrng, int N) {
    __shared__ int cnt[256];
    __shared__ int sm[256];
    __shared__ int lofs[256];
    int b = blockIdx.x;
    int tid = threadIdx.x;
    int beg = b * CAP, end = beg + bcur[b];
    int nbase = b << BSH;
    if (tid < 256) cnt[tid] = 0;
    __syncthreads();
    for (int i = beg + tid; i < end; i += 512)
        atomicAdd(&cnt[pairs[i] & BMASK], 1);
    __syncthreads();
    int v = (tid < 256) ? cnt[tid] : 0;
    if (tid < 256) sm[tid] = v;
    __syncthreads();
    int acc = v;
    for (int off = 1; off < 256; off <<= 1) {
        int t = (tid >= off && tid < 256) ? sm[tid - off] : 0;
        __syncthreads();
        if (tid < 256) { acc += t; sm[tid] = acc; }
        __syncthreads();
    }
    if (tid < 256) {
        int excl = acc - v;
        lofs[tid] = excl;
        int n = nbase + tid;
        if (n < N) rowrng[n] = make_int2(beg + excl, beg + excl + v);
        cnt[tid] = 0;
    }
    __syncthreads();
    for (int i = beg + tid; i < end; i += 512) {
        unsigned p = pairs[i];
        int dl = p & BMASK;
        int idx = atomicAdd(&cnt[dl], 1);
        src_s[beg + lofs[dl] + idx] = p >> BSH;
    }
}

// ---------------- fused attn + softmax + aggregation + silu ----------------
// 8 lanes per node; lanes 0-3 head0, 4-7 head1 (head-blocked transposed row layout, r14).
// 8 edges in flight (proven best: VGPR ~48-64, occupancy ~30%).
__global__ __launch_bounds__(256) void k_fused(const int2* __restrict__ rowrng,
        const int* __restrict__ src_s, const unsigned short* __restrict__ xlh,
        const unsigned short* __restrict__ xrh, const float* __restrict__ att,
        const float* __restrict__ bias, float* __restrict__ out, int N)
{
    int n = blockIdx.x * 32 + (threadIdx.x >> 3);
    int jf = threadIdx.x & 7;
    if (n >= N) return;
    int hsel = jf >> 2, l4 = jf & 3;
    const uint4* xl4 = (const uint4*)xlh + jf;
    f32x2 xr2[4], a06[4], a04[4];
    {
        uint4 u = ((const uint4*)xrh)[(size_t)n * 8 + jf];
        xr2[0] = dec2(u.x); xr2[1] = dec2(u.y);
        xr2[2] = dec2(u.z); xr2[3] = dec2(u.w);
        int cb = hsel * 32 + 4 * l4;
#pragma unroll
        for (int k = 0; k < 4; ++k) {
            float c0 = att[cb + k], c1 = att[cb + 16 + k];
            a06[k] = (f32x2){0.6f * c0, 0.6f * c1};
            a04[k] = (f32x2){0.4f * c0, 0.4f * c1};
        }
    }
    int2 rr = rowrng[n];
    float ssum = 0.f;
    f32x2 acc2[4] = {(f32x2){0.f,0.f}, (f32x2){0.f,0.f}, (f32x2){0.f,0.f}, (f32x2){0.f,0.f}};

#define EDGE_BODY(u)                                                      \
    {                                                                     \
        f32x2 v0 = dec2((u).x), v1 = dec2((u).y), v2 = dec2((u).z), v3 = dec2((u).w); \
        f32x2 h0 = v0 + xr2[0], h1 = v1 + xr2[1], h2 = v2 + xr2[2], h3 = v3 + xr2[3]; \
        f32x2 pa = h0 * a06[0]; pa += h1 * a06[1]; pa += h2 * a06[2]; pa += h3 * a06[3]; \
        pa += abs2(h0) * a04[0]; pa += abs2(h1) * a04[1];                 \
        pa += abs2(h2) * a04[2]; pa += abs2(h3) * a04[3];                 \
        float p = pa.x + pa.y;                                            \
        p = qsum(p);                                                      \
        float wq = __expf(p);                                             \
        ssum += wq;                                                       \
        f32x2 ws = (f32x2){wq, wq};                                       \
        acc2[0] += ws * v0; acc2[1] += ws * v1;                           \
        acc2[2] += ws * v2; acc2[3] += ws * v3;                           \
    }

    int i = rr.x;
    for (; i + 8 <= rr.y; i += 8) {
        uint4 u[8];
#pragma unroll
        for (int q = 0; q < 8; ++q)
            u[q] = xl4[((uint)src_s[i + q] << 3)];
#pragma unroll
        for (int q = 0; q < 8; ++q)
            EDGE_BODY(u[q]);
    }
    if (i + 4 <= rr.y) {
        uint4 u[4];
#pragma unroll
        for (int q = 0; q < 4; ++q)
            u[q] = xl4[((uint)src_s[i + q] << 3)];
#pragma unroll
        for (int q = 0; q < 4; ++q)
            EDGE_BODY(u[q]);
        i += 4;
    }
    for (; i < rr.y; ++i) {
        uint4 u0 = xl4[((uint)src_s[i] << 3)];
        EDGE_BODY(u0);
    }
#undef EDGE_BODY

    float inv = 1.f / ssum;
    float o[8];
#pragma unroll
    for (int q = 0; q < 4; ++q) {
        float vx = acc2[q].x * inv, vy = acc2[q].y * inv;
        o[2 * q]     = (vx + __shfl_xor(vx, 4)) * 0.5f;   // head-mean: partner holds col+32
        o[2 * q + 1] = (vy + __shfl_xor(vy, 4)) * 0.5f;
    }
    if (jf < 4) {
        float4 b0 = ((const float4*)bias)[l4];
        float4 b1 = *(const float4*)(bias + 16 + 4 * l4);
        float4 r0, r1;
        r0.x = o[0] + b0.x; r0.y = o[2] + b0.y; r0.z = o[4] + b0.z; r0.w = o[6] + b0.w;
        r1.x = o[1] + b1.x; r1.y = o[3] + b1.y; r1.z = o[5] + b1.z; r1.w = o[7] + b1.w;
        r0.x = r0.x / (1.f + __expf(-r0.x));
        r0.y = r0.y / (1.f + __expf(-r0.y));
        r0.z = r0.z / (1.f + __expf(-r0.z));
        r0.w = r0.w / (1.f + __expf(-r0.w));
        r1.x = r1.x / (1.f + __expf(-r1.x));
        r1.y = r1.y / (1.f + __expf(-r1.y));
        r1.z = r1.z / (1.f + __expf(-r1.z));
        r1.w = r1.w / (1.f + __expf(-r1.w));
        ((float4*)out)[(size_t)n * 8 + l4]     = r0;
        ((float4*)out)[(size_t)n * 8 + 4 + l4] = r1;
    }
}

extern "C" void kernel_launch(void* const* d_in, const int* in_sizes, int n_in,
                              void* d_out, int out_size, void* d_ws, size_t ws_size,
                              hipStream_t stream) {
    const float* x    = (const float*)d_in[0];
    const float* Wl   = (const float*)d_in[1];
    const float* bl   = (const float*)d_in[2];
    const float* Wr   = (const float*)d_in[3];
    const float* br   = (const float*)d_in[4];
    const float* att  = (const float*)d_in[5];
    const float* bias = (const float*)d_in[6];
    const int*   ei   = (const int*)d_in[7];
    float* out = (float*)d_out;

    const int N = in_sizes[0] / 128;
    const int E = in_sizes[7] / 2;
    const int T = E + N;                          // edges incl. self loops
    const int NB = (N + (1 << BSH) - 1) >> BSH;   // 391 buckets

    char* p = (char*)d_ws;
    auto take = [&](size_t bytes) {
        char* r = p;
        p += (bytes + 255) & ~(size_t)255;
        return r;
    };
    unsigned short* xlh = (unsigned short*)take((size_t)N * 64 * 2);
    unsigned short* xrh = (unsigned short*)take((size_t)N * 64 * 2);
    unsigned* pairs  = (unsigned*)take((size_t)NB * CAP * 4);
    int*      src_s  = (int*)take((size_t)NB * CAP * 4);
    int2*     rowrng = (int2*)take((size_t)N * 8);
    int*      bcur   = (int*)take((size_t)NB * 4);
    unsigned short* Wt = (unsigned short*)take((size_t)128 * 128 * 2);

    k_prep <<<8,                   256, 0, stream>>>(Wl, Wr, Wt, bcur, NB);
    k_gemm <<<(N + 63) / 64,       512, 0, stream>>>(x, Wt, bl, br, xlh, xrh, N);
    k_scatA<<<(T + ACH - 1) / ACH, 256, 0, stream>>>(ei, bcur, pairs, E, T, NB);
    k_scatB<<<NB,                  512, 0, stream>>>(pairs, bcur, src_s, rowrng, N);
    k_fused<<<(N + 31) / 32,       256, 0, stream>>>(rowrng, src_s, xlh, xrh, att, bias, out, N);
}

// Round 18
// 108.919 us; speedup vs baseline: 1.1320x; 1.0993x over previous
//
#include <hip/hip_runtime.h>
#include <math.h>

#define BSH 9                       // 512 nodes per bucket
#define BMASK ((1 << BSH) - 1)
#define CAP 12288                   // per-bucket pair capacity (mean 8676, sigma 93)
#define ACH 8192                    // edges per scatA block (long runs -> full-line writes)

typedef unsigned int uint;
typedef __attribute__((ext_vector_type(8))) short bf16x8;
typedef __attribute__((ext_vector_type(4))) float f32x4;
typedef __attribute__((ext_vector_type(2))) float f32x2;

static __device__ __forceinline__ unsigned short f2bf(float f) {
    uint u = __float_as_uint(f);
    return (unsigned short)((u + 0x7fffu + ((u >> 16) & 1u)) >> 16);
}

// pack 8 consecutive fp32 (two f32x4) -> bf16x8 via HW cvt (RNE), src0 -> low half
static __device__ __forceinline__ bf16x8 pack8(f32x4 a, f32x4 b) {
    uint p0, p1, p2, p3;
    asm("v_cvt_pk_bf16_f32 %0, %1, %2" : "=v"(p0) : "v"(a.x), "v"(a.y));
    asm("v_cvt_pk_bf16_f32 %0, %1, %2" : "=v"(p1) : "v"(a.z), "v"(a.w));
    asm("v_cvt_pk_bf16_f32 %0, %1, %2" : "=v"(p2) : "v"(b.x), "v"(b.y));
    asm("v_cvt_pk_bf16_f32 %0, %1, %2" : "=v"(p3) : "v"(b.z), "v"(b.w));
    uint4 u = make_uint4(p0, p1, p2, p3);
    return *(bf16x8*)&u;
}

static __device__ __forceinline__ uint pk2(float a, float b) {
    uint d;
    asm("v_cvt_pk_bf16_f32 %0, %1, %2" : "=v"(d) : "v"(a), "v"(b));
    return d;
}

static __device__ __forceinline__ f32x2 dec2(uint u) {
    f32x2 r;
    r.x = __uint_as_float(u << 16);
    r.y = __uint_as_float(u & 0xffff0000u);
    return r;
}

static __device__ __forceinline__ f32x2 abs2(f32x2 h) {
    f32x2 r;
    r.x = __uint_as_float(__float_as_uint(h.x) & 0x7fffffffu);
    r.y = __uint_as_float(__float_as_uint(h.y) & 0x7fffffffu);
    return r;
}

// sum over 4-lane quads via DPP (no LDS port): xor1 then xor2
static __device__ __forceinline__ float qsum(float p) {
    p += __uint_as_float(__builtin_amdgcn_mov_dpp(__float_as_uint(p), 0xB1, 0xF, 0xF, true));
    p += __uint_as_float(__builtin_amdgcn_mov_dpp(__float_as_uint(p), 0x4E, 0xF, 0xF, true));
    return p;
}

// ---------------- prep: fragment-major bf16 weight table + bcur zeroing ----------------
// Slot si = ks*512 + j*64 + hi*16 + lo holds W^T[n=j*16+lo][k=ks*32+hi*8 .. +8].
__global__ __launch_bounds__(256) void k_prep(const float* __restrict__ Wl,
                                              const float* __restrict__ Wr,
                                              unsigned short* __restrict__ Wt,
                                              int* __restrict__ bcur, int NB) {
    if (blockIdx.x == 0)
        for (int i = threadIdx.x; i < NB; i += 256) bcur[i] = 0;
    int si = blockIdx.x * 256 + threadIdx.x;   // 0..2047
    int lo = si & 15;
    int hi = (si >> 4) & 3;
    int j  = (si >> 6) & 7;
    int ks = si >> 9;
    int n  = j * 16 + lo;
    int kb = ks * 32 + hi * 8;
    const float* Wp = (n < 64) ? (Wl + n) : (Wr + (n - 64));
    unsigned short v[8];
#pragma unroll
    for (int m = 0; m < 8; ++m)
        v[m] = f2bf(Wp[(size_t)(kb + m) * 64]);
    uint4 pk;
    pk.x = (uint)v[0] | ((uint)v[1] << 16);
    pk.y = (uint)v[2] | ((uint)v[3] << 16);
    pk.z = (uint)v[4] | ((uint)v[5] << 16);
    pk.w = (uint)v[6] | ((uint)v[7] << 16);
    *(uint4*)(Wt + (size_t)si * 8) = pk;
}

// ---------------- MFMA dual GEMM: BM=64, 8 waves = 4 row-groups x 2 col-halves ----------
// Wave (wr, wc): rows base+wr*16..+15, cols wc*64..+63 (wc=0 -> xlh, wc=1 -> xrh).
// Output row layout (xlh and xrh), co-designed with k_fused (verified r14):
//   position 2*lo + t      <-> col t*16 + lo       (head 0)
//   position 32 + 2*lo + t <-> col 32 + t*16 + lo  (head 1)
__global__ __launch_bounds__(512) void k_gemm(
        const float* __restrict__ x, const unsigned short* __restrict__ Wt,
        const float* __restrict__ bl, const float* __restrict__ br,
        unsigned short* __restrict__ xlh, unsigned short* __restrict__ xrh, int N)
{
    const int t = threadIdx.x;
    const int base = blockIdx.x * 64;
    const int w  = t >> 6;              // wave 0..7
    const int wr = w >> 1;              // row group 0..3
    const int wc = w & 1;               // col half: 0 = xl, 1 = xr
    const int lo = t & 15;
    const int hi = (t & 63) >> 4;
    int rowa = base + wr * 16 + lo;
    const f32x4* x4 = (const f32x4*)x + (size_t)(rowa < N ? rowa : N - 1) * 32;
    const bf16x8* Wf = (const bf16x8*)Wt;

    f32x4 acc[4];
#pragma unroll
    for (int j = 0; j < 4; ++j)
        acc[j] = (f32x4){0.f, 0.f, 0.f, 0.f};

#pragma unroll
    for (int ks = 0; ks < 4; ++ks) {
        int f4 = ks * 8 + hi * 2;
        int sbase = ks * 512 + wc * 256 + hi * 16 + lo;   // wc*4 frags * 64 slots
        bf16x8 av = pack8(x4[f4], x4[f4 + 1]);
        bf16x8 bv[4];
#pragma unroll
        for (int j = 0; j < 4; ++j)
            bv[j] = Wf[sbase + j * 64];
#pragma unroll
        for (int j = 0; j < 4; ++j)
            acc[j] = __builtin_amdgcn_mfma_f32_16x16x32_bf16(av, bv[j], acc[j], 0, 0, 0);
    }

    // ---- epilogue: D row = base + wr*16 + hi*4 + q, col = (wc*4+j)*16 + lo ----
    const float* bb = wc ? br : bl;
    unsigned short* dst = wc ? xrh : xlh;
    float bv4[4];
#pragma unroll
    for (int t2 = 0; t2 < 4; ++t2)
        bv4[t2] = bb[t2 * 16 + lo];
#pragma unroll
    for (int q = 0; q < 4; ++q) {
        int row = base + wr * 16 + hi * 4 + q;
        if (row < N) {
            size_t rb = (size_t)row * 64;
            *(uint*)(dst + rb + 2 * lo)      = pk2(acc[0][q] + bv4[0], acc[1][q] + bv4[1]);
            *(uint*)(dst + rb + 32 + 2 * lo) = pk2(acc[2][q] + bv4[2], acc[3][q] + bv4[3]);
        }
    }
}

// ---------------- scatA: blocked coarse scatter, 512 thr, long chunks ----------------
__global__ __launch_bounds__(512) void k_scatA(const int* __restrict__ ei, int* __restrict__ bcur,
                                               unsigned* __restrict__ pairs, int E, int T, int NB) {
    __shared__ int h[256];
    __shared__ int basem[256];
    int tid = threadIdx.x;
    int b0 = blockIdx.x * ACH;
    int cnt = min(ACH, T - b0);
    if (tid < 256) h[tid] = 0;
    __syncthreads();
    for (int i = tid; i < cnt; i += 512) {
        int t = b0 + i;
        int d = (t < E) ? ei[E + t] : (t - E);
        atomicAdd(&h[d >> BSH], 1);
    }
    __syncthreads();
    if (tid < NB) {
        int c = h[tid];
        basem[tid] = c ? (tid * CAP + atomicAdd(&bcur[tid], c)) : 0;
    }
    __syncthreads();
    if (tid < 256) h[tid] = 0;
    __syncthreads();
    for (int i = tid; i < cnt; i += 512) {
        int t = b0 + i;
        int s, d;
        if (t < E) { s = ei[t]; d = ei[E + t]; } else { s = t - E; d = s; }
        int b = d >> BSH;
        int idx = atomicAdd(&h[b], 1);
        pairs[basem[b] + idx] = ((unsigned)s << BSH) | (unsigned)(d & BMASK);
    }
}

// ---------------- pass B: per-bucket degree count + scan + fine scatter + rowrng ----------------
__global__ __launch_bounds__(512) void k_scatB(const unsigned* __restrict__ pairs,
                                               const int* __restrict__ bcur,
                                               int* __restrict__ src_s, int2* __restrict__ rowrng, int N) {
    __shared__ int cnt[512];
    __shared__ int sm[512];
    __shared__ int lofs[512];
    int b = blockIdx.x;
    int beg = b * CAP, end = beg + bcur[b];
    int nbase = b << BSH;
    cnt[threadIdx.x] = 0;
    __syncthreads();
    for (int i = beg + threadIdx.x; i < end; i += 512)
        atomicAdd(&cnt[pairs[i] & BMASK], 1);
    __syncthreads();
    int v = cnt[threadIdx.x];
    sm[threadIdx.x] = v;
    __syncthreads();
    int acc = v;
    for (int off = 1; off < 512; off <<= 1) {
        int t = (threadIdx.x >= off) ? sm[threadIdx.x - off] : 0;
        __syncthreads();
        acc += t;
        sm[threadIdx.x] = acc;
        __syncthreads();
    }
    int excl = acc - v;
    lofs[threadIdx.x] = excl;
    int n = nbase + threadIdx.x;
    if (n < N) rowrng[n] = make_int2(beg + excl, beg + excl + v);
    cnt[threadIdx.x] = 0;
    __syncthreads();
    for (int i = beg + threadIdx.x; i < end; i += 512) {
        unsigned p = pairs[i];
        int dl = p & BMASK;
        int idx = atomicAdd(&cnt[dl], 1);
        src_s[beg + lofs[dl] + idx] = p >> BSH;
    }
}

// ---------------- fused attn + softmax + aggregation + silu ----------------
// 8 lanes per node; lanes 0-3 head0, 4-7 head1 (head-blocked transposed row layout, r14).
// 8 edges in flight (proven best: VGPR ~48-64, occupancy ~30%).
__global__ __launch_bounds__(256) void k_fused(const int2* __restrict__ rowrng,
        const int* __restrict__ src_s, const unsigned short* __restrict__ xlh,
        const unsigned short* __restrict__ xrh, const float* __restrict__ att,
        const float* __restrict__ bias, float* __restrict__ out, int N)
{
    int n = blockIdx.x * 32 + (threadIdx.x >> 3);
    int jf = threadIdx.x & 7;
    if (n >= N) return;
    int hsel = jf >> 2, l4 = jf & 3;
    const uint4* xl4 = (const uint4*)xlh + jf;
    f32x2 xr2[4], a06[4], a04[4];
    {
        uint4 u = ((const uint4*)xrh)[(size_t)n * 8 + jf];
        xr2[0] = dec2(u.x); xr2[1] = dec2(u.y);
        xr2[2] = dec2(u.z); xr2[3] = dec2(u.w);
        int cb = hsel * 32 + 4 * l4;
#pragma unroll
        for (int k = 0; k < 4; ++k) {
            float c0 = att[cb + k], c1 = att[cb + 16 + k];
            a06[k] = (f32x2){0.6f * c0, 0.6f * c1};
            a04[k] = (f32x2){0.4f * c0, 0.4f * c1};
        }
    }
    int2 rr = rowrng[n];
    float ssum = 0.f;
    f32x2 acc2[4] = {(f32x2){0.f,0.f}, (f32x2){0.f,0.f}, (f32x2){0.f,0.f}, (f32x2){0.f,0.f}};

#define EDGE_BODY(u)                                                      \
    {                                                                     \
        f32x2 v0 = dec2((u).x), v1 = dec2((u).y), v2 = dec2((u).z), v3 = dec2((u).w); \
        f32x2 h0 = v0 + xr2[0], h1 = v1 + xr2[1], h2 = v2 + xr2[2], h3 = v3 + xr2[3]; \
        f32x2 pa = h0 * a06[0]; pa += h1 * a06[1]; pa += h2 * a06[2]; pa += h3 * a06[3]; \
        pa += abs2(h0) * a04[0]; pa += abs2(h1) * a04[1];                 \
        pa += abs2(h2) * a04[2]; pa += abs2(h3) * a04[3];                 \
        float p = pa.x + pa.y;                                            \
        p = qsum(p);                                                      \
        float wq = __expf(p);                                             \
        ssum += wq;                                                       \
        f32x2 ws = (f32x2){wq, wq};                                       \
        acc2[0] += ws * v0; acc2[1] += ws * v1;                           \
        acc2[2] += ws * v2; acc2[3] += ws * v3;                           \
    }

    int i = rr.x;
    for (; i + 8 <= rr.y; i += 8) {
        uint4 u[8];
#pragma unroll
        for (int q = 0; q < 8; ++q)
            u[q] = xl4[((uint)src_s[i + q] << 3)];
#pragma unroll
        for (int q = 0; q < 8; ++q)
            EDGE_BODY(u[q]);
    }
    if (i + 4 <= rr.y) {
        uint4 u[4];
#pragma unroll
        for (int q = 0; q < 4; ++q)
            u[q] = xl4[((uint)src_s[i + q] << 3)];
#pragma unroll
        for (int q = 0; q < 4; ++q)
            EDGE_BODY(u[q]);
        i += 4;
    }
    for (; i < rr.y; ++i) {
        uint4 u0 = xl4[((uint)src_s[i] << 3)];
        EDGE_BODY(u0);
    }
#undef EDGE_BODY

    float inv = 1.f / ssum;
    float o[8];
#pragma unroll
    for (int q = 0; q < 4; ++q) {
        float vx = acc2[q].x * inv, vy = acc2[q].y * inv;
        o[2 * q]     = (vx + __shfl_xor(vx, 4)) * 0.5f;   // head-mean: partner holds col+32
        o[2 * q + 1] = (vy + __shfl_xor(vy, 4)) * 0.5f;
    }
    if (jf < 4) {
        float4 b0 = ((const float4*)bias)[l4];
        float4 b1 = *(const float4*)(bias + 16 + 4 * l4);
        float4 r0, r1;
        r0.x = o[0] + b0.x; r0.y = o[2] + b0.y; r0.z = o[4] + b0.z; r0.w = o[6] + b0.w;
        r1.x = o[1] + b1.x; r1.y = o[3] + b1.y; r1.z = o[5] + b1.z; r1.w = o[7] + b1.w;
        r0.x = r0.x / (1.f + __expf(-r0.x));
        r0.y = r0.y / (1.f + __expf(-r0.y));
        r0.z = r0.z / (1.f + __expf(-r0.z));
        r0.w = r0.w / (1.f + __expf(-r0.w));
        r1.x = r1.x / (1.f + __expf(-r1.x));
        r1.y = r1.y / (1.f + __expf(-r1.y));
        r1.z = r1.z / (1.f + __expf(-r1.z));
        r1.w = r1.w / (1.f + __expf(-r1.w));
        ((float4*)out)[(size_t)n * 8 + l4]     = r0;
        ((float4*)out)[(size_t)n * 8 + 4 + l4] = r1;
    }
}

extern "C" void kernel_launch(void* const* d_in, const int* in_sizes, int n_in,
                              void* d_out, int out_size, void* d_ws, size_t ws_size,
                              hipStream_t stream) {
    const float* x    = (const float*)d_in[0];
    const float* Wl   = (const float*)d_in[1];
    const float* bl   = (const float*)d_in[2];
    const float* Wr   = (const float*)d_in[3];
    const float* br   = (const float*)d_in[4];
    const float* att  = (const float*)d_in[5];
    const float* bias = (const float*)d_in[6];
    const int*   ei   = (const int*)d_in[7];
    float* out = (float*)d_out;

    const int N = in_sizes[0] / 128;
    const int E = in_sizes[7] / 2;
    const int T = E + N;                          // edges incl. self loops
    const int NB = (N + (1 << BSH) - 1) >> BSH;   // 196 buckets

    char* p = (char*)d_ws;
    auto take = [&](size_t bytes) {
        char* r = p;
        p += (bytes + 255) & ~(size_t)255;
        return r;
    };
    unsigned short* xlh = (unsigned short*)take((size_t)N * 64 * 2);
    unsigned short* xrh = (unsigned short*)take((size_t)N * 64 * 2);
    unsigned* pairs  = (unsigned*)take((size_t)NB * CAP * 4);
    int*      src_s  = (int*)take((size_t)NB * CAP * 4);
    int2*     rowrng = (int2*)take((size_t)N * 8);
    int*      bcur   = (int*)take((size_t)NB * 4);
    unsigned short* Wt = (unsigned short*)take((size_t)128 * 128 * 2);

    k_prep <<<8,                   256, 0, stream>>>(Wl, Wr, Wt, bcur, NB);
    k_gemm <<<(N + 63) / 64,       512, 0, stream>>>(x, Wt, bl, br, xlh, xrh, N);
    k_scatA<<<(T + ACH - 1) / ACH, 512, 0, stream>>>(ei, bcur, pairs, E, T, NB);
    k_scatB<<<NB,                  512, 0, stream>>>(pairs, bcur, src_s, rowrng, N);
    k_fused<<<(N + 31) / 32,       256, 0, stream>>>(rowrng, src_s, xlh, xrh, att, bias, out, N);
}